// Round 12
// baseline (518.283 us; speedup 1.0000x reference)
//
#include <hip/hip_runtime.h>
#include <hip/hip_bf16.h>

#define DIN 300
#define KP  320            // K padded to multiple of 32 for MFMA
#define NH  64

typedef __bf16 bf16x8 __attribute__((ext_vector_type(8)));
typedef float  f32x4  __attribute__((ext_vector_type(4)));

__device__ inline float wave_sum(float v){
#pragma unroll
  for (int m = 32; m >= 1; m >>= 1) v += __shfl_xor(v, m, 64);
  return v;
}

// ---------- fused prep: cvtX | cvtW | hist (independent work, one launch) ----------
__global__ __launch_bounds__(256) void k_prep(const float* __restrict__ X,
                                              __hip_bfloat16* __restrict__ Xb,
                                              const float* __restrict__ Wpb,
                                              const float* __restrict__ Wnb,
                                              __hip_bfloat16* __restrict__ Wtb,
                                              const int* __restrict__ pr, const int* __restrict__ nr,
                                              int* __restrict__ cp, int* __restrict__ cn,
                                              int E, int N){
  int b = blockIdx.x;
  if (b < N){                          // X row -> bf16 padded
    const float* xr = X + (size_t)b * DIN;
    __hip_bfloat16* o = Xb + (size_t)b * KP;
    for (int k = threadIdx.x; k < KP; k += 256)
      o[k] = __float2bfloat16(k < DIN ? xr[k] : 0.f);
  } else if (b < N + 256){             // W col -> transposed bf16 padded
    int c = b - N;
    int sel = c >> 6, jj = c & 63;
    const float* W = (sel < 2 ? Wpb : Wnb) + (size_t)(sel & 1) * DIN * NH + jj;
    __hip_bfloat16* o = Wtb + (size_t)c * KP;
    for (int k = threadIdx.x; k < KP; k += 256)
      o[k] = __float2bfloat16(k < DIN ? W[(size_t)k * NH] : 0.f);
  } else {                             // edge histogram
    int i = (b - N - 256) * 256 + threadIdx.x;
    if (i < E){ atomicAdd(cp + pr[i], 1); atomicAdd(cn + nr[i], 1); }
  }
}

// ---------- XW[N][256] = Xb @ Wcat  (MFMA bf16) ----------
__global__ __launch_bounds__(256) void k_gemm_base(const __hip_bfloat16* __restrict__ Xb,
                                                   const __hip_bfloat16* __restrict__ Wtb,
                                                   float* __restrict__ XW){
  const int wave = threadIdx.x >> 6, lane = threadIdx.x & 63;
  const int ti = blockIdx.y * 64 + wave * 16;     // row tile (16 rows/wave)
  const int cj = blockIdx.x * 64;                 // col tile
  const int r0 = lane & 15, kq = (lane >> 4) * 8;
  const unsigned short* Xp = (const unsigned short*)Xb;
  const unsigned short* Wp = (const unsigned short*)Wtb;
  f32x4 acc[4] = {};
  for (int ks = 0; ks < KP / 32; ++ks){
    int kb = ks * 32 + kq;
    bf16x8 a = *(const bf16x8*)(Xp + (size_t)(ti + r0) * KP + kb);
#pragma unroll
    for (int js = 0; js < 4; ++js){
      bf16x8 b = *(const bf16x8*)(Wp + (size_t)(cj + js * 16 + r0) * KP + kb);
      acc[js] = __builtin_amdgcn_mfma_f32_16x16x32_bf16(a, b, acc[js], 0, 0, 0);
    }
  }
  const int orow = ti + (lane >> 4) * 4;
  const int oc = cj + (lane & 15);
#pragma unroll
  for (int js = 0; js < 4; ++js)
#pragma unroll
    for (int i = 0; i < 4; ++i)
      XW[(size_t)(orow + i) * 256 + oc + js * 16] = acc[js][i];
}

__global__ __launch_bounds__(1024) void k_scan(const int* __restrict__ c0, int* __restrict__ o0,
                                               const int* __restrict__ c1, int* __restrict__ o1, int n){
  const int* cnt = blockIdx.x ? c1 : c0;
  int* off = blockIdx.x ? o1 : o0;
  __shared__ int lds[1024];
  int t = threadIdx.x;
  int ept = n >> 10;
  int s = 0;
  for (int i = 0; i < ept; ++i) s += cnt[t * ept + i];
  lds[t] = s; __syncthreads();
  for (int d = 1; d < 1024; d <<= 1){
    int add = (t >= d) ? lds[t - d] : 0;
    __syncthreads();
    lds[t] += add;
    __syncthreads();
  }
  int base = t ? lds[t - 1] : 0;
  for (int i = 0; i < ept; ++i){ off[t * ept + i] = base; base += cnt[t * ept + i]; }
}

__global__ void k_fill(const int* __restrict__ pr, const int* __restrict__ pc,
                       const int* __restrict__ nr, const int* __restrict__ nc,
                       const int* __restrict__ op, const int* __restrict__ on,
                       int* __restrict__ curp, int* __restrict__ curn,
                       int* __restrict__ adjp, int* __restrict__ adjn, int E){
  int i = blockIdx.x * 256 + threadIdx.x;
  if (i < E){
    int r = pr[i]; int p = atomicAdd(curp + r, 1); adjp[op[r] + p] = pc[i];
    r = nr[i];     p = atomicAdd(curn + r, 1);     adjn[on[r] + p] = nc[i];
  }
}

// ---------- base layer: mean-gather + self + bias, l2norm, tanh ----------
__device__ inline float gather_mean(const float* __restrict__ XW, const int* __restrict__ adj,
                                    int base, int d, int col){
  float s = 0.f; int j = 0;
  for (; j + 4 <= d; j += 4){
    int n0 = adj[base + j], n1 = adj[base + j + 1], n2 = adj[base + j + 2], n3 = adj[base + j + 3];
    s += XW[(size_t)n0 * 256 + col] + XW[(size_t)n1 * 256 + col]
       + XW[(size_t)n2 * 256 + col] + XW[(size_t)n3 * 256 + col];
  }
  for (; j < d; ++j) s += XW[(size_t)adj[base + j] * 256 + col];
  return s / (float)(d > 0 ? d : 1);
}

__global__ __launch_bounds__(256) void k_base(const float* __restrict__ XW,
    const int* __restrict__ adjp, const int* __restrict__ offp, const int* __restrict__ cntp,
    const int* __restrict__ adjn, const int* __restrict__ offn, const int* __restrict__ cntn,
    const float* __restrict__ bp, const float* __restrict__ bn,
    float* __restrict__ hp, float* __restrict__ hn){
  const int wave = threadIdx.x >> 6, lane = threadIdx.x & 63;
  const int node = blockIdx.x * 4 + wave;
  {
    float s = gather_mean(XW, adjp, offp[node], cntp[node], lane);
    float pre = s + XW[(size_t)node * 256 + 64 + lane] + bp[lane];
    float nrm = sqrtf(wave_sum(pre * pre));
    hp[(size_t)node * 64 + lane] = tanhf(pre / fmaxf(nrm, 1e-12f));
  }
  {
    float s = gather_mean(XW, adjn, offn[node], cntn[node], lane + 128);
    float pre = s + XW[(size_t)node * 256 + 192 + lane] + bn[lane];
    float nrm = sqrtf(wave_sum(pre * pre));
    hn[(size_t)node * 64 + lane] = tanhf(pre / fmaxf(nrm, 1e-12f));
  }
}

// ---------- deep layer (fused aggregates + both 192x64 GEMMs + norms + X_mol) ----------
__global__ __launch_bounds__(256) void k_deep(const float* __restrict__ hp, const float* __restrict__ hn,
    const int* __restrict__ adjp, const int* __restrict__ offp, const int* __restrict__ cntp,
    const int* __restrict__ adjn, const int* __restrict__ offn, const int* __restrict__ cntn,
    const float* __restrict__ Wpd, const float* __restrict__ bpd,
    const float* __restrict__ Wnd, const float* __restrict__ bnd,
    float* __restrict__ xmol, __hip_bfloat16* __restrict__ Xmb){
  const int wave = threadIdx.x >> 6, lane = threadIdx.x & 63;
  const int node = blockIdx.x * 4 + wave;
  const float mhp = hp[(size_t)node * 64 + lane];
  const float mhn = hn[(size_t)node * 64 + lane];
  float a1p = 0.f, a1n = 0.f;
  {
    int d = cntp[node], base = offp[node]; int j = 0;
    for (; j + 2 <= d; j += 2){
      int n0 = adjp[base + j], n1 = adjp[base + j + 1];
      a1p += hp[(size_t)n0 * 64 + lane] + hp[(size_t)n1 * 64 + lane];
      a1n += hn[(size_t)n0 * 64 + lane] + hn[(size_t)n1 * 64 + lane];
    }
    for (; j < d; ++j){ int n0 = adjp[base + j]; a1p += hp[(size_t)n0 * 64 + lane]; a1n += hn[(size_t)n0 * 64 + lane]; }
    float inv = 1.f / (float)(d > 0 ? d : 1); a1p *= inv; a1n *= inv;
  }
  float a2p = 0.f, a2n = 0.f;
  {
    int d = cntn[node], base = offn[node]; int j = 0;
    for (; j + 2 <= d; j += 2){
      int n0 = adjn[base + j], n1 = adjn[base + j + 1];
      a2p += hn[(size_t)n0 * 64 + lane] + hn[(size_t)n1 * 64 + lane];
      a2n += hp[(size_t)n0 * 64 + lane] + hp[(size_t)n1 * 64 + lane];
    }
    for (; j < d; ++j){ int n0 = adjn[base + j]; a2p += hn[(size_t)n0 * 64 + lane]; a2n += hp[(size_t)n0 * 64 + lane]; }
    float inv = 1.f / (float)(d > 0 ? d : 1); a2p *= inv; a2n *= inv;
  }
  float accp = bpd[lane], accn = bnd[lane];
#pragma unroll 4
  for (int k = 0; k < 64; ++k){
    float p1 = __shfl(a1p, k, 64), p2 = __shfl(a2p, k, 64), p3 = __shfl(mhp, k, 64);
    float q1 = __shfl(a1n, k, 64), q2 = __shfl(a2n, k, 64), q3 = __shfl(mhn, k, 64);
    accp += p1 * Wpd[k * 64 + lane] + p2 * Wpd[(64 + k) * 64 + lane] + p3 * Wpd[(128 + k) * 64 + lane];
    accn += q1 * Wnd[k * 64 + lane] + q2 * Wnd[(64 + k) * 64 + lane] + q3 * Wnd[(128 + k) * 64 + lane];
  }
  float np = sqrtf(wave_sum(accp * accp));
  float h2p = tanhf(accp / fmaxf(np, 1e-12f));
  float nn = sqrtf(wave_sum(accn * accn));
  float h2n = tanhf(accn / fmaxf(nn, 1e-12f));
  float nz = sqrtf(wave_sum(h2p * h2p + h2n * h2n));
  float xp = h2p / fmaxf(nz, 1e-12f);
  float xn = h2n / fmaxf(nz, 1e-12f);
  xmol[(size_t)node * 128 + lane] = xp;
  xmol[(size_t)node * 128 + 64 + lane] = xn;
  Xmb[(size_t)node * 128 + lane] = __float2bfloat16(xp);
  Xmb[(size_t)node * 128 + 64 + lane] = __float2bfloat16(xn);
}

// ---------- pred = (Xm @ Xm^T) * mask ; per-block loss partials ----------
// NO LDS transpose: epilogue works directly in the MFMA C-layout. For fixed
// (js,i) a scalar access = 4 rows x 16 consecutive cols = 4 x 64B segments
// (full HBM granules). Payload is 32 scalar VGPRs -> the compiler can keep the
// whole 32-load burst live (unlike 16 f32x4 = 128 VGPRs). LDS ~0 -> occupancy
// VGPR-bound (~8 waves/SIMD). sched_barrier(0) pins the burst against sinking.
__global__ __launch_bounds__(256) void k_pred(const __hip_bfloat16* __restrict__ Xmb,
    const float* __restrict__ mask, const float* __restrict__ labels,
    float* __restrict__ pred, float* __restrict__ partial, int N){
  const int wave = threadIdx.x >> 6, lane = threadIdx.x & 63;
  const int ti = blockIdx.y * 64 + wave * 16;
  const int tj = blockIdx.x * 64;
  const int r0 = lane & 15, kq = (lane >> 4) * 8;
  const unsigned short* X = (const unsigned short*)Xmb;
  f32x4 acc[4] = {};
#pragma unroll
  for (int ks = 0; ks < 4; ++ks){
    int kb = ks * 32 + kq;
    bf16x8 a = *(const bf16x8*)(X + (size_t)(ti + r0) * 128 + kb);
#pragma unroll
    for (int js = 0; js < 4; ++js){
      bf16x8 b = *(const bf16x8*)(X + (size_t)(tj + js * 16 + r0) * 128 + kb);
      acc[js] = __builtin_amdgcn_mfma_f32_16x16x32_bf16(a, b, acc[js], 0, 0, 0);
    }
  }
  const int orow = ti + (lane >> 4) * 4;
  const int oc = tj + (lane & 15);
  // batched 32-scalar-load burst (independent of acc)
  float m[16], lb[16];
#pragma unroll
  for (int js = 0; js < 4; ++js)
#pragma unroll
    for (int i = 0; i < 4; ++i){
      size_t idx = (size_t)(orow + i) * N + oc + js * 16;
      m[js * 4 + i]  = __builtin_nontemporal_load(mask + idx);
      lb[js * 4 + i] = __builtin_nontemporal_load(labels + idx);
    }
  __builtin_amdgcn_sched_barrier(0);   // keep the burst batched; no sinking
  float lsum = 0.f;
#pragma unroll
  for (int js = 0; js < 4; ++js)
#pragma unroll
    for (int i = 0; i < 4; ++i){
      float pv = acc[js][i] * m[js * 4 + i];
      float d = pv - lb[js * 4 + i];
      lsum += d * d;
      size_t idx = (size_t)(orow + i) * N + oc + js * 16;
      __builtin_nontemporal_store(pv, pred + idx);
    }
  lsum = wave_sum(lsum);
  __shared__ float wsum[4];
  if (lane == 0) wsum[wave] = lsum;
  __syncthreads();
  if (threadIdx.x == 0)
    partial[blockIdx.y * gridDim.x + blockIdx.x] = wsum[0] + wsum[1] + wsum[2] + wsum[3];
}

__global__ __launch_bounds__(1024) void k_loss_fin(const float* __restrict__ partial,
                                                   float* __restrict__ out, float inv, int n){
  float s = 0.f;
  for (int i = threadIdx.x; i < n; i += 1024) s += partial[i];
  s = wave_sum(s);
  __shared__ float ws[16];
  if ((threadIdx.x & 63) == 0) ws[threadIdx.x >> 6] = s;
  __syncthreads();
  if (threadIdx.x == 0){
    float t = 0.f;
#pragma unroll
    for (int w = 0; w < 16; ++w) t += ws[w];
    out[0] = t * inv;
  }
}

extern "C" void kernel_launch(void* const* d_in, const int* in_sizes, int n_in,
                              void* d_out, int out_size, void* d_ws, size_t ws_size,
                              hipStream_t stream){
  const float* X      = (const float*)d_in[0];
  const int*   pe     = (const int*)d_in[1];
  const int*   ne     = (const int*)d_in[2];
  const float* labels = (const float*)d_in[3];
  const float* mask   = (const float*)d_in[4];
  const float* Wpb    = (const float*)d_in[5];
  const float* bpb    = (const float*)d_in[6];
  const float* Wnb    = (const float*)d_in[7];
  const float* bnb    = (const float*)d_in[8];
  const float* Wpd    = (const float*)d_in[9];
  const float* bpd    = (const float*)d_in[10];
  const float* Wnd    = (const float*)d_in[11];
  const float* bnd    = (const float*)d_in[12];
  const int N = in_sizes[0] / DIN;       // 8192
  const int E = in_sizes[1] / 2;         // 262144

  char* ws = (char*)d_ws;
  size_t off = 0;
  auto alloc = [&](size_t bytes){ void* p = ws + off; off = (off + bytes + 255) & ~(size_t)255; return p; };
  float* XW            = (float*)alloc((size_t)N * 256 * 4);
  float* hp            = (float*)alloc((size_t)N * 64 * 4);
  float* hn            = (float*)alloc((size_t)N * 64 * 4);
  __hip_bfloat16* Xmb  = (__hip_bfloat16*)alloc((size_t)N * 128 * 2);
  __hip_bfloat16* Xb   = (__hip_bfloat16*)alloc((size_t)N * KP * 2);
  __hip_bfloat16* Wtb  = (__hip_bfloat16*)alloc((size_t)256 * KP * 2);
  int* adjp            = (int*)alloc((size_t)E * 4);
  int* adjn            = (int*)alloc((size_t)E * 4);
  char* zbase = ws + off;                 // zeroed region start
  int* cntp            = (int*)alloc((size_t)N * 4);
  int* cntn            = (int*)alloc((size_t)N * 4);
  int* curp            = (int*)alloc((size_t)N * 4);
  int* curn            = (int*)alloc((size_t)N * 4);
  size_t zbytes = (size_t)((ws + off) - zbase);
  int* offp            = (int*)alloc((size_t)N * 4);
  int* offn            = (int*)alloc((size_t)N * 4);
  float* partial       = (float*)alloc((size_t)(N / 64) * (N / 64) * 4);
  (void)ws_size; (void)n_in; (void)out_size;

  float* out_loss = (float*)d_out;
  float* out_xmol = out_loss + 1;
  float* out_pred = out_xmol + (size_t)N * 128;

  hipMemsetAsync(zbase, 0, zbytes, stream);
  k_prep<<<N + 256 + (E + 255) / 256, 256, 0, stream>>>(X, Xb, Wpb, Wnb, Wtb,
                                                        pe, ne, cntp, cntn, E, N);
  k_gemm_base<<<dim3(4, N / 64), 256, 0, stream>>>(Xb, Wtb, XW);
  k_scan<<<2, 1024, 0, stream>>>(cntp, offp, cntn, offn, N);
  k_fill<<<(E + 255) / 256, 256, 0, stream>>>(pe, pe + E, ne, ne + E, offp, offn, curp, curn, adjp, adjn, E);
  k_base<<<N / 4, 256, 0, stream>>>(XW, adjp, offp, cntp, adjn, offn, cntn, bpb, bnb, hp, hn);
  k_deep<<<N / 4, 256, 0, stream>>>(hp, hn, adjp, offp, cntp, adjn, offn, cntn,
                                    Wpd, bpd, Wnd, bnd, out_xmol, Xmb);
  k_pred<<<dim3(N / 64, N / 64), 256, 0, stream>>>(Xmb, mask, labels, out_pred, partial, N);
  k_loss_fin<<<1, 1024, 0, stream>>>(partial, out_loss, 1.0f / ((float)N * (float)N), (N / 64) * (N / 64));
}

// Round 13
// 367.925 us; speedup vs baseline: 1.4087x; 1.4087x over previous
//
#include <hip/hip_runtime.h>
#include <hip/hip_bf16.h>

#define DIN 300
#define KP  320            // K padded to multiple of 32 for MFMA
#define NH  64

typedef __bf16 bf16x8 __attribute__((ext_vector_type(8)));
typedef float  f32x4  __attribute__((ext_vector_type(4)));

__device__ inline float wave_sum(float v){
#pragma unroll
  for (int m = 32; m >= 1; m >>= 1) v += __shfl_xor(v, m, 64);
  return v;
}

// ---------- fused prep: cvtX | cvtW | hist (independent work, one launch) ----------
__global__ __launch_bounds__(256) void k_prep(const float* __restrict__ X,
                                              __hip_bfloat16* __restrict__ Xb,
                                              const float* __restrict__ Wpb,
                                              const float* __restrict__ Wnb,
                                              __hip_bfloat16* __restrict__ Wtb,
                                              const int* __restrict__ pr, const int* __restrict__ nr,
                                              int* __restrict__ cp, int* __restrict__ cn,
                                              int E, int N){
  int b = blockIdx.x;
  if (b < N){                          // X row -> bf16 padded
    const float* xr = X + (size_t)b * DIN;
    __hip_bfloat16* o = Xb + (size_t)b * KP;
    for (int k = threadIdx.x; k < KP; k += 256)
      o[k] = __float2bfloat16(k < DIN ? xr[k] : 0.f);
  } else if (b < N + 256){             // W col -> transposed bf16 padded
    int c = b - N;
    int sel = c >> 6, jj = c & 63;
    const float* W = (sel < 2 ? Wpb : Wnb) + (size_t)(sel & 1) * DIN * NH + jj;
    __hip_bfloat16* o = Wtb + (size_t)c * KP;
    for (int k = threadIdx.x; k < KP; k += 256)
      o[k] = __float2bfloat16(k < DIN ? W[(size_t)k * NH] : 0.f);
  } else {                             // edge histogram
    int i = (b - N - 256) * 256 + threadIdx.x;
    if (i < E){ atomicAdd(cp + pr[i], 1); atomicAdd(cn + nr[i], 1); }
  }
}

// ---------- XW[N][256] = Xb @ Wcat  (MFMA bf16) ----------
__global__ __launch_bounds__(256) void k_gemm_base(const __hip_bfloat16* __restrict__ Xb,
                                                   const __hip_bfloat16* __restrict__ Wtb,
                                                   float* __restrict__ XW){
  const int wave = threadIdx.x >> 6, lane = threadIdx.x & 63;
  const int ti = blockIdx.y * 64 + wave * 16;     // row tile (16 rows/wave)
  const int cj = blockIdx.x * 64;                 // col tile
  const int r0 = lane & 15, kq = (lane >> 4) * 8;
  const unsigned short* Xp = (const unsigned short*)Xb;
  const unsigned short* Wp = (const unsigned short*)Wtb;
  f32x4 acc[4] = {};
  for (int ks = 0; ks < KP / 32; ++ks){
    int kb = ks * 32 + kq;
    bf16x8 a = *(const bf16x8*)(Xp + (size_t)(ti + r0) * KP + kb);
#pragma unroll
    for (int js = 0; js < 4; ++js){
      bf16x8 b = *(const bf16x8*)(Wp + (size_t)(cj + js * 16 + r0) * KP + kb);
      acc[js] = __builtin_amdgcn_mfma_f32_16x16x32_bf16(a, b, acc[js], 0, 0, 0);
    }
  }
  const int orow = ti + (lane >> 4) * 4;
  const int oc = cj + (lane & 15);
#pragma unroll
  for (int js = 0; js < 4; ++js)
#pragma unroll
    for (int i = 0; i < 4; ++i)
      XW[(size_t)(orow + i) * 256 + oc + js * 16] = acc[js][i];
}

__global__ __launch_bounds__(1024) void k_scan(const int* __restrict__ c0, int* __restrict__ o0,
                                               const int* __restrict__ c1, int* __restrict__ o1, int n){
  const int* cnt = blockIdx.x ? c1 : c0;
  int* off = blockIdx.x ? o1 : o0;
  __shared__ int lds[1024];
  int t = threadIdx.x;
  int ept = n >> 10;
  int s = 0;
  for (int i = 0; i < ept; ++i) s += cnt[t * ept + i];
  lds[t] = s; __syncthreads();
  for (int d = 1; d < 1024; d <<= 1){
    int add = (t >= d) ? lds[t - d] : 0;
    __syncthreads();
    lds[t] += add;
    __syncthreads();
  }
  int base = t ? lds[t - 1] : 0;
  for (int i = 0; i < ept; ++i){ off[t * ept + i] = base; base += cnt[t * ept + i]; }
}

__global__ void k_fill(const int* __restrict__ pr, const int* __restrict__ pc,
                       const int* __restrict__ nr, const int* __restrict__ nc,
                       const int* __restrict__ op, const int* __restrict__ on,
                       int* __restrict__ curp, int* __restrict__ curn,
                       int* __restrict__ adjp, int* __restrict__ adjn, int E){
  int i = blockIdx.x * 256 + threadIdx.x;
  if (i < E){
    int r = pr[i]; int p = atomicAdd(curp + r, 1); adjp[op[r] + p] = pc[i];
    r = nr[i];     p = atomicAdd(curn + r, 1);     adjn[on[r] + p] = nc[i];
  }
}

// ---------- base layer: mean-gather + self + bias, l2norm, tanh ----------
__device__ inline float gather_mean(const float* __restrict__ XW, const int* __restrict__ adj,
                                    int base, int d, int col){
  float s = 0.f; int j = 0;
  for (; j + 4 <= d; j += 4){
    int n0 = adj[base + j], n1 = adj[base + j + 1], n2 = adj[base + j + 2], n3 = adj[base + j + 3];
    s += XW[(size_t)n0 * 256 + col] + XW[(size_t)n1 * 256 + col]
       + XW[(size_t)n2 * 256 + col] + XW[(size_t)n3 * 256 + col];
  }
  for (; j < d; ++j) s += XW[(size_t)adj[base + j] * 256 + col];
  return s / (float)(d > 0 ? d : 1);
}

__global__ __launch_bounds__(256) void k_base(const float* __restrict__ XW,
    const int* __restrict__ adjp, const int* __restrict__ offp, const int* __restrict__ cntp,
    const int* __restrict__ adjn, const int* __restrict__ offn, const int* __restrict__ cntn,
    const float* __restrict__ bp, const float* __restrict__ bn,
    float* __restrict__ hp, float* __restrict__ hn){
  const int wave = threadIdx.x >> 6, lane = threadIdx.x & 63;
  const int node = blockIdx.x * 4 + wave;
  {
    float s = gather_mean(XW, adjp, offp[node], cntp[node], lane);
    float pre = s + XW[(size_t)node * 256 + 64 + lane] + bp[lane];
    float nrm = sqrtf(wave_sum(pre * pre));
    hp[(size_t)node * 64 + lane] = tanhf(pre / fmaxf(nrm, 1e-12f));
  }
  {
    float s = gather_mean(XW, adjn, offn[node], cntn[node], lane + 128);
    float pre = s + XW[(size_t)node * 256 + 192 + lane] + bn[lane];
    float nrm = sqrtf(wave_sum(pre * pre));
    hn[(size_t)node * 64 + lane] = tanhf(pre / fmaxf(nrm, 1e-12f));
  }
}

// ---------- deep layer (fused aggregates + both 192x64 GEMMs + norms + X_mol) ----------
__global__ __launch_bounds__(256) void k_deep(const float* __restrict__ hp, const float* __restrict__ hn,
    const int* __restrict__ adjp, const int* __restrict__ offp, const int* __restrict__ cntp,
    const int* __restrict__ adjn, const int* __restrict__ offn, const int* __restrict__ cntn,
    const float* __restrict__ Wpd, const float* __restrict__ bpd,
    const float* __restrict__ Wnd, const float* __restrict__ bnd,
    float* __restrict__ xmol, __hip_bfloat16* __restrict__ Xmb){
  const int wave = threadIdx.x >> 6, lane = threadIdx.x & 63;
  const int node = blockIdx.x * 4 + wave;
  const float mhp = hp[(size_t)node * 64 + lane];
  const float mhn = hn[(size_t)node * 64 + lane];
  float a1p = 0.f, a1n = 0.f;
  {
    int d = cntp[node], base = offp[node]; int j = 0;
    for (; j + 2 <= d; j += 2){
      int n0 = adjp[base + j], n1 = adjp[base + j + 1];
      a1p += hp[(size_t)n0 * 64 + lane] + hp[(size_t)n1 * 64 + lane];
      a1n += hn[(size_t)n0 * 64 + lane] + hn[(size_t)n1 * 64 + lane];
    }
    for (; j < d; ++j){ int n0 = adjp[base + j]; a1p += hp[(size_t)n0 * 64 + lane]; a1n += hn[(size_t)n0 * 64 + lane]; }
    float inv = 1.f / (float)(d > 0 ? d : 1); a1p *= inv; a1n *= inv;
  }
  float a2p = 0.f, a2n = 0.f;
  {
    int d = cntn[node], base = offn[node]; int j = 0;
    for (; j + 2 <= d; j += 2){
      int n0 = adjn[base + j], n1 = adjn[base + j + 1];
      a2p += hn[(size_t)n0 * 64 + lane] + hn[(size_t)n1 * 64 + lane];
      a2n += hp[(size_t)n0 * 64 + lane] + hp[(size_t)n1 * 64 + lane];
    }
    for (; j < d; ++j){ int n0 = adjn[base + j]; a2p += hn[(size_t)n0 * 64 + lane]; a2n += hp[(size_t)n0 * 64 + lane]; }
    float inv = 1.f / (float)(d > 0 ? d : 1); a2p *= inv; a2n *= inv;
  }
  float accp = bpd[lane], accn = bnd[lane];
#pragma unroll 4
  for (int k = 0; k < 64; ++k){
    float p1 = __shfl(a1p, k, 64), p2 = __shfl(a2p, k, 64), p3 = __shfl(mhp, k, 64);
    float q1 = __shfl(a1n, k, 64), q2 = __shfl(a2n, k, 64), q3 = __shfl(mhn, k, 64);
    accp += p1 * Wpd[k * 64 + lane] + p2 * Wpd[(64 + k) * 64 + lane] + p3 * Wpd[(128 + k) * 64 + lane];
    accn += q1 * Wnd[k * 64 + lane] + q2 * Wnd[(64 + k) * 64 + lane] + q3 * Wnd[(128 + k) * 64 + lane];
  }
  float np = sqrtf(wave_sum(accp * accp));
  float h2p = tanhf(accp / fmaxf(np, 1e-12f));
  float nn = sqrtf(wave_sum(accn * accn));
  float h2n = tanhf(accn / fmaxf(nn, 1e-12f));
  float nz = sqrtf(wave_sum(h2p * h2p + h2n * h2n));
  float xp = h2p / fmaxf(nz, 1e-12f);
  float xn = h2n / fmaxf(nz, 1e-12f);
  xmol[(size_t)node * 128 + lane] = xp;
  xmol[(size_t)node * 128 + 64 + lane] = xn;
  Xmb[(size_t)node * 128 + lane] = __float2bfloat16(xp);
  Xmb[(size_t)node * 128 + 64 + lane] = __float2bfloat16(xn);
}

// ---------- pred = (Xm @ Xm^T) * mask ; per-block loss partials ----------
// R6 structure (16x128 wave tile, LDS transpose, f32x4 consume = 256B write
// segments) + keep-alive pinned load burst: empty asm reading each load's
// result forces ALL 16 f32x4 loads to issue before any consume (scheduler
// cannot sink a load past an asm that reads its def). launch_bounds(256,3)
// gives the allocator ~170 VGPRs for the 64-VGPR payload.
__global__ __launch_bounds__(256, 3) void k_pred(const __hip_bfloat16* __restrict__ Xmb,
    const float* __restrict__ mask, const float* __restrict__ labels,
    float* __restrict__ pred, float* __restrict__ partial, int N){
  const int wave = threadIdx.x >> 6, lane = threadIdx.x & 63;
  const int ti = blockIdx.y * 64 + wave * 16;
  const int tj = blockIdx.x * 128;
  const int r0 = lane & 15, kq = (lane >> 4) * 8;
  const unsigned short* X = (const unsigned short*)Xmb;
  f32x4 acc[2][4] = {};
#pragma unroll
  for (int ks = 0; ks < 4; ++ks){
    int kb = ks * 32 + kq;
    bf16x8 a = *(const bf16x8*)(X + (size_t)(ti + r0) * 128 + kb);
#pragma unroll
    for (int pan = 0; pan < 2; ++pan)
#pragma unroll
      for (int js = 0; js < 4; ++js){
        bf16x8 b = *(const bf16x8*)(X + (size_t)(tj + pan * 64 + js * 16 + r0) * 128 + kb);
        acc[pan][js] = __builtin_amdgcn_mfma_f32_16x16x32_bf16(a, b, acc[pan][js], 0, 0, 0);
      }
  }
  // full mask/label burst; keep-alives pin every load above the consume phase
  const int hi = lane >> 5, c = lane & 31;
  f32x4 m[8], lb[8];
#pragma unroll
  for (int g = 0; g < 8; ++g){
    size_t idx = (size_t)(ti + g * 2 + hi) * N + tj + c * 4;
    m[g]  = __builtin_nontemporal_load((const f32x4*)(mask + idx));
    lb[g] = __builtin_nontemporal_load((const f32x4*)(labels + idx));
  }
#pragma unroll
  for (int g = 0; g < 8; ++g)
    asm volatile("" : "+v"(m[g]), "+v"(lb[g]));
  // transpose 16x128 wave tile through LDS; pad 132 (528B rows, 16B-aligned)
  __shared__ float tile[4][16][132];
  __shared__ float wsum[4];
  const int rb = (lane >> 4) * 4, c16 = lane & 15;
#pragma unroll
  for (int pan = 0; pan < 2; ++pan)
#pragma unroll
    for (int js = 0; js < 4; ++js)
#pragma unroll
      for (int i = 0; i < 4; ++i)
        tile[wave][rb + i][pan * 64 + js * 16 + c16] = acc[pan][js][i];
  float lsum = 0.f;
#pragma unroll
  for (int g = 0; g < 8; ++g){
    int row = g * 2 + hi;
    f32x4 a = *(const f32x4*)&tile[wave][row][c * 4];
    f32x4 pv = a * m[g];
    f32x4 d = pv - lb[g];
    lsum += d[0]*d[0] + d[1]*d[1] + d[2]*d[2] + d[3]*d[3];
    size_t idx = (size_t)(ti + row) * N + tj + c * 4;
    // pred base is at odd float offset in d_out -> scalar NT stores
    // (16 lanes x 4 consecutive floats per row -> 256B segments)
    __builtin_nontemporal_store(pv[0], pred + idx);
    __builtin_nontemporal_store(pv[1], pred + idx + 1);
    __builtin_nontemporal_store(pv[2], pred + idx + 2);
    __builtin_nontemporal_store(pv[3], pred + idx + 3);
  }
  lsum = wave_sum(lsum);
  if (lane == 0) wsum[wave] = lsum;
  __syncthreads();
  if (threadIdx.x == 0)
    partial[blockIdx.y * gridDim.x + blockIdx.x] = wsum[0] + wsum[1] + wsum[2] + wsum[3];
}

__global__ __launch_bounds__(1024) void k_loss_fin(const float* __restrict__ partial,
                                                   float* __restrict__ out, float inv, int n){
  float s = 0.f;
  for (int i = threadIdx.x; i < n; i += 1024) s += partial[i];
  s = wave_sum(s);
  __shared__ float ws[16];
  if ((threadIdx.x & 63) == 0) ws[threadIdx.x >> 6] = s;
  __syncthreads();
  if (threadIdx.x == 0){
    float t = 0.f;
#pragma unroll
    for (int w = 0; w < 16; ++w) t += ws[w];
    out[0] = t * inv;
  }
}

extern "C" void kernel_launch(void* const* d_in, const int* in_sizes, int n_in,
                              void* d_out, int out_size, void* d_ws, size_t ws_size,
                              hipStream_t stream){
  const float* X      = (const float*)d_in[0];
  const int*   pe     = (const int*)d_in[1];
  const int*   ne     = (const int*)d_in[2];
  const float* labels = (const float*)d_in[3];
  const float* mask   = (const float*)d_in[4];
  const float* Wpb    = (const float*)d_in[5];
  const float* bpb    = (const float*)d_in[6];
  const float* Wnb    = (const float*)d_in[7];
  const float* bnb    = (const float*)d_in[8];
  const float* Wpd    = (const float*)d_in[9];
  const float* bpd    = (const float*)d_in[10];
  const float* Wnd    = (const float*)d_in[11];
  const float* bnd    = (const float*)d_in[12];
  const int N = in_sizes[0] / DIN;       // 8192
  const int E = in_sizes[1] / 2;         // 262144

  char* ws = (char*)d_ws;
  size_t off = 0;
  auto alloc = [&](size_t bytes){ void* p = ws + off; off = (off + bytes + 255) & ~(size_t)255; return p; };
  float* XW            = (float*)alloc((size_t)N * 256 * 4);
  float* hp            = (float*)alloc((size_t)N * 64 * 4);
  float* hn            = (float*)alloc((size_t)N * 64 * 4);
  __hip_bfloat16* Xmb  = (__hip_bfloat16*)alloc((size_t)N * 128 * 2);
  __hip_bfloat16* Xb   = (__hip_bfloat16*)alloc((size_t)N * KP * 2);
  __hip_bfloat16* Wtb  = (__hip_bfloat16*)alloc((size_t)256 * KP * 2);
  int* adjp            = (int*)alloc((size_t)E * 4);
  int* adjn            = (int*)alloc((size_t)E * 4);
  char* zbase = ws + off;                 // zeroed region start
  int* cntp            = (int*)alloc((size_t)N * 4);
  int* cntn            = (int*)alloc((size_t)N * 4);
  int* curp            = (int*)alloc((size_t)N * 4);
  int* curn            = (int*)alloc((size_t)N * 4);
  size_t zbytes = (size_t)((ws + off) - zbase);
  int* offp            = (int*)alloc((size_t)N * 4);
  int* offn            = (int*)alloc((size_t)N * 4);
  float* partial       = (float*)alloc((size_t)(N / 64) * (N / 128) * 4);
  (void)ws_size; (void)n_in; (void)out_size;

  float* out_loss = (float*)d_out;
  float* out_xmol = out_loss + 1;
  float* out_pred = out_xmol + (size_t)N * 128;

  hipMemsetAsync(zbase, 0, zbytes, stream);
  k_prep<<<N + 256 + (E + 255) / 256, 256, 0, stream>>>(X, Xb, Wpb, Wnb, Wtb,
                                                        pe, ne, cntp, cntn, E, N);
  k_gemm_base<<<dim3(4, N / 64), 256, 0, stream>>>(Xb, Wtb, XW);
  k_scan<<<2, 1024, 0, stream>>>(cntp, offp, cntn, offn, N);
  k_fill<<<(E + 255) / 256, 256, 0, stream>>>(pe, pe + E, ne, ne + E, offp, offn, curp, curn, adjp, adjn, E);
  k_base<<<N / 4, 256, 0, stream>>>(XW, adjp, offp, cntp, adjn, offn, cntn, bpb, bnb, hp, hn);
  k_deep<<<N / 4, 256, 0, stream>>>(hp, hn, adjp, offp, cntp, adjn, offn, cntn,
                                    Wpd, bpd, Wnd, bnd, out_xmol, Xmb);
  k_pred<<<dim3(N / 128, N / 64), 256, 0, stream>>>(Xmb, mask, labels, out_pred, partial, N);
  k_loss_fin<<<1, 1024, 0, stream>>>(partial, out_loss, 1.0f / ((float)N * (float)N), (N / 64) * (N / 128));
}

// Round 14
// 344.607 us; speedup vs baseline: 1.5040x; 1.0677x over previous
//
#include <hip/hip_runtime.h>
#include <hip/hip_bf16.h>

#define DIN 300
#define KP  320            // K padded to multiple of 32 for MFMA
#define NH  64

typedef __bf16 bf16x8 __attribute__((ext_vector_type(8)));
typedef float  f32x4  __attribute__((ext_vector_type(4)));
typedef short  s16x4  __attribute__((ext_vector_type(4)));

__device__ inline float wave_sum(float v){
#pragma unroll
  for (int m = 32; m >= 1; m >>= 1) v += __shfl_xor(v, m, 64);
  return v;
}

// ---------- fused prep: cvtX | cvtW | hist (independent work, one launch) ----------
__global__ __launch_bounds__(256) void k_prep(const float* __restrict__ X,
                                              __hip_bfloat16* __restrict__ Xb,
                                              const float* __restrict__ Wpb,
                                              const float* __restrict__ Wnb,
                                              __hip_bfloat16* __restrict__ Wtb,
                                              const int* __restrict__ pr, const int* __restrict__ nr,
                                              int* __restrict__ cp, int* __restrict__ cn,
                                              int E, int N){
  int b = blockIdx.x;
  if (b < N){                          // X row -> bf16 padded (vectorized: f32x4 -> 4xbf16)
    const float* xr = X + (size_t)b * DIN;           // row base 1200B = 16B aligned
    unsigned short* o = (unsigned short*)(Xb + (size_t)b * KP);
    int k = threadIdx.x;               // 80 groups of 4 elements (KP=320)
    if (k < 80){
      s16x4 v;
      if (k < 75){                     // 75*4 = 300 = DIN
        f32x4 x = *(const f32x4*)(xr + k * 4);
#pragma unroll
        for (int j = 0; j < 4; ++j){
          union { float f; unsigned u; } cv; cv.f = x[j];
          // round-to-nearest-even bf16
          unsigned r = (cv.u + 0x7FFF + ((cv.u >> 16) & 1)) >> 16;
          v[j] = (short)r;
        }
      } else v = (s16x4){0,0,0,0};
      *(s16x4*)(o + k * 4) = v;
    }
  } else if (b < N + 256){             // W col -> transposed bf16 padded
    int c = b - N;
    int sel = c >> 6, jj = c & 63;
    const float* W = (sel < 2 ? Wpb : Wnb) + (size_t)(sel & 1) * DIN * NH + jj;
    __hip_bfloat16* o = Wtb + (size_t)c * KP;
    for (int k = threadIdx.x; k < KP; k += 256)
      o[k] = __float2bfloat16(k < DIN ? W[(size_t)k * NH] : 0.f);
  } else {                             // edge histogram
    int i = (b - N - 256) * 256 + threadIdx.x;
    if (i < E){ atomicAdd(cp + pr[i], 1); atomicAdd(cn + nr[i], 1); }
  }
}

// ---------- XW[N][256] = Xb @ Wcat  (MFMA bf16) ----------
__global__ __launch_bounds__(256) void k_gemm_base(const __hip_bfloat16* __restrict__ Xb,
                                                   const __hip_bfloat16* __restrict__ Wtb,
                                                   float* __restrict__ XW){
  const int wave = threadIdx.x >> 6, lane = threadIdx.x & 63;
  const int ti = blockIdx.y * 64 + wave * 16;     // row tile (16 rows/wave)
  const int cj = blockIdx.x * 64;                 // col tile
  const int r0 = lane & 15, kq = (lane >> 4) * 8;
  const unsigned short* Xp = (const unsigned short*)Xb;
  const unsigned short* Wp = (const unsigned short*)Wtb;
  f32x4 acc[4] = {};
  for (int ks = 0; ks < KP / 32; ++ks){
    int kb = ks * 32 + kq;
    bf16x8 a = *(const bf16x8*)(Xp + (size_t)(ti + r0) * KP + kb);
#pragma unroll
    for (int js = 0; js < 4; ++js){
      bf16x8 b = *(const bf16x8*)(Wp + (size_t)(cj + js * 16 + r0) * KP + kb);
      acc[js] = __builtin_amdgcn_mfma_f32_16x16x32_bf16(a, b, acc[js], 0, 0, 0);
    }
  }
  const int orow = ti + (lane >> 4) * 4;
  const int oc = cj + (lane & 15);
#pragma unroll
  for (int js = 0; js < 4; ++js)
#pragma unroll
    for (int i = 0; i < 4; ++i)
      XW[(size_t)(orow + i) * 256 + oc + js * 16] = acc[js][i];
}

__global__ __launch_bounds__(1024) void k_scan(const int* __restrict__ c0, int* __restrict__ o0,
                                               const int* __restrict__ c1, int* __restrict__ o1, int n){
  const int* cnt = blockIdx.x ? c1 : c0;
  int* off = blockIdx.x ? o1 : o0;
  __shared__ int lds[1024];
  int t = threadIdx.x;
  int ept = n >> 10;
  int s = 0;
  for (int i = 0; i < ept; ++i) s += cnt[t * ept + i];
  lds[t] = s; __syncthreads();
  for (int d = 1; d < 1024; d <<= 1){
    int add = (t >= d) ? lds[t - d] : 0;
    __syncthreads();
    lds[t] += add;
    __syncthreads();
  }
  int base = t ? lds[t - 1] : 0;
  for (int i = 0; i < ept; ++i){ off[t * ept + i] = base; base += cnt[t * ept + i]; }
}

__global__ void k_fill(const int* __restrict__ pr, const int* __restrict__ pc,
                       const int* __restrict__ nr, const int* __restrict__ nc,
                       const int* __restrict__ op, const int* __restrict__ on,
                       int* __restrict__ curp, int* __restrict__ curn,
                       int* __restrict__ adjp, int* __restrict__ adjn, int E){
  int i = blockIdx.x * 256 + threadIdx.x;
  if (i < E){
    int r = pr[i]; int p = atomicAdd(curp + r, 1); adjp[op[r] + p] = pc[i];
    r = nr[i];     p = atomicAdd(curn + r, 1);     adjn[on[r] + p] = nc[i];
  }
}

// ---------- base layer: mean-gather + self + bias, l2norm, tanh ----------
__device__ inline float gather_mean(const float* __restrict__ XW, const int* __restrict__ adj,
                                    int base, int d, int col){
  float s0 = 0.f, s1 = 0.f, s2 = 0.f, s3 = 0.f;
  int j = 0;
  for (; j + 8 <= d; j += 8){
    int n0 = adj[base + j],     n1 = adj[base + j + 1], n2 = adj[base + j + 2], n3 = adj[base + j + 3];
    int n4 = adj[base + j + 4], n5 = adj[base + j + 5], n6 = adj[base + j + 6], n7 = adj[base + j + 7];
    s0 += XW[(size_t)n0 * 256 + col] + XW[(size_t)n4 * 256 + col];
    s1 += XW[(size_t)n1 * 256 + col] + XW[(size_t)n5 * 256 + col];
    s2 += XW[(size_t)n2 * 256 + col] + XW[(size_t)n6 * 256 + col];
    s3 += XW[(size_t)n3 * 256 + col] + XW[(size_t)n7 * 256 + col];
  }
  for (; j < d; ++j) s0 += XW[(size_t)adj[base + j] * 256 + col];
  float s = (s0 + s1) + (s2 + s3);
  return s / (float)(d > 0 ? d : 1);
}

__global__ __launch_bounds__(256) void k_base(const float* __restrict__ XW,
    const int* __restrict__ adjp, const int* __restrict__ offp, const int* __restrict__ cntp,
    const int* __restrict__ adjn, const int* __restrict__ offn, const int* __restrict__ cntn,
    const float* __restrict__ bp, const float* __restrict__ bn,
    float* __restrict__ hp, float* __restrict__ hn){
  const int wave = threadIdx.x >> 6, lane = threadIdx.x & 63;
  const int node = blockIdx.x * 4 + wave;
  {
    float s = gather_mean(XW, adjp, offp[node], cntp[node], lane);
    float pre = s + XW[(size_t)node * 256 + 64 + lane] + bp[lane];
    float nrm = sqrtf(wave_sum(pre * pre));
    hp[(size_t)node * 64 + lane] = tanhf(pre / fmaxf(nrm, 1e-12f));
  }
  {
    float s = gather_mean(XW, adjn, offn[node], cntn[node], lane + 128);
    float pre = s + XW[(size_t)node * 256 + 192 + lane] + bn[lane];
    float nrm = sqrtf(wave_sum(pre * pre));
    hn[(size_t)node * 64 + lane] = tanhf(pre / fmaxf(nrm, 1e-12f));
  }
}

// ---------- deep layer (fused aggregates + both 192x64 GEMMs + norms + X_mol) ----------
__global__ __launch_bounds__(256) void k_deep(const float* __restrict__ hp, const float* __restrict__ hn,
    const int* __restrict__ adjp, const int* __restrict__ offp, const int* __restrict__ cntp,
    const int* __restrict__ adjn, const int* __restrict__ offn, const int* __restrict__ cntn,
    const float* __restrict__ Wpd, const float* __restrict__ bpd,
    const float* __restrict__ Wnd, const float* __restrict__ bnd,
    float* __restrict__ xmol, __hip_bfloat16* __restrict__ Xmb){
  const int wave = threadIdx.x >> 6, lane = threadIdx.x & 63;
  const int node = blockIdx.x * 4 + wave;
  const float mhp = hp[(size_t)node * 64 + lane];
  const float mhn = hn[(size_t)node * 64 + lane];
  float a1p = 0.f, a1n = 0.f;
  {
    int d = cntp[node], base = offp[node]; int j = 0;
    for (; j + 4 <= d; j += 4){
      int n0 = adjp[base + j], n1 = adjp[base + j + 1];
      int n2 = adjp[base + j + 2], n3 = adjp[base + j + 3];
      a1p += (hp[(size_t)n0 * 64 + lane] + hp[(size_t)n1 * 64 + lane])
           + (hp[(size_t)n2 * 64 + lane] + hp[(size_t)n3 * 64 + lane]);
      a1n += (hn[(size_t)n0 * 64 + lane] + hn[(size_t)n1 * 64 + lane])
           + (hn[(size_t)n2 * 64 + lane] + hn[(size_t)n3 * 64 + lane]);
    }
    for (; j < d; ++j){ int n0 = adjp[base + j]; a1p += hp[(size_t)n0 * 64 + lane]; a1n += hn[(size_t)n0 * 64 + lane]; }
    float inv = 1.f / (float)(d > 0 ? d : 1); a1p *= inv; a1n *= inv;
  }
  float a2p = 0.f, a2n = 0.f;
  {
    int d = cntn[node], base = offn[node]; int j = 0;
    for (; j + 4 <= d; j += 4){
      int n0 = adjn[base + j], n1 = adjn[base + j + 1];
      int n2 = adjn[base + j + 2], n3 = adjn[base + j + 3];
      a2p += (hn[(size_t)n0 * 64 + lane] + hn[(size_t)n1 * 64 + lane])
           + (hn[(size_t)n2 * 64 + lane] + hn[(size_t)n3 * 64 + lane]);
      a2n += (hp[(size_t)n0 * 64 + lane] + hp[(size_t)n1 * 64 + lane])
           + (hp[(size_t)n2 * 64 + lane] + hp[(size_t)n3 * 64 + lane]);
    }
    for (; j < d; ++j){ int n0 = adjn[base + j]; a2p += hn[(size_t)n0 * 64 + lane]; a2n += hp[(size_t)n0 * 64 + lane]; }
    float inv = 1.f / (float)(d > 0 ? d : 1); a2p *= inv; a2n *= inv;
  }
  float accp = bpd[lane], accn = bnd[lane];
#pragma unroll 4
  for (int k = 0; k < 64; ++k){
    float p1 = __shfl(a1p, k, 64), p2 = __shfl(a2p, k, 64), p3 = __shfl(mhp, k, 64);
    float q1 = __shfl(a1n, k, 64), q2 = __shfl(a2n, k, 64), q3 = __shfl(mhn, k, 64);
    accp += p1 * Wpd[k * 64 + lane] + p2 * Wpd[(64 + k) * 64 + lane] + p3 * Wpd[(128 + k) * 64 + lane];
    accn += q1 * Wnd[k * 64 + lane] + q2 * Wnd[(64 + k) * 64 + lane] + q3 * Wnd[(128 + k) * 64 + lane];
  }
  float np = sqrtf(wave_sum(accp * accp));
  float h2p = tanhf(accp / fmaxf(np, 1e-12f));
  float nn = sqrtf(wave_sum(accn * accn));
  float h2n = tanhf(accn / fmaxf(nn, 1e-12f));
  float nz = sqrtf(wave_sum(h2p * h2p + h2n * h2n));
  float xp = h2p / fmaxf(nz, 1e-12f);
  float xn = h2n / fmaxf(nz, 1e-12f);
  xmol[(size_t)node * 128 + lane] = xp;
  xmol[(size_t)node * 128 + 64 + lane] = xn;
  Xmb[(size_t)node * 128 + lane] = __float2bfloat16(xp);
  Xmb[(size_t)node * 128 + 64 + lane] = __float2bfloat16(xn);
}

// ---------- pred = (Xm @ Xm^T) * mask ; per-block loss partials ----------
// EXACT R6 structure (measured best: 201us, 2.8 TB/s HBM + L3-served reads
// ~= 3.8 TB/s effective): 16x128 wave tile, burst of 16 f32x4 NT loads issued
// right after MFMA (overlaps LDS transpose), f32x4 consume (256B segments),
// default occupancy (VGPR 64, ~41%).
__global__ __launch_bounds__(256) void k_pred(const __hip_bfloat16* __restrict__ Xmb,
    const float* __restrict__ mask, const float* __restrict__ labels,
    float* __restrict__ pred, float* __restrict__ partial, int N){
  const int wave = threadIdx.x >> 6, lane = threadIdx.x & 63;
  const int ti = blockIdx.y * 64 + wave * 16;
  const int tj = blockIdx.x * 128;
  const int r0 = lane & 15, kq = (lane >> 4) * 8;
  const unsigned short* X = (const unsigned short*)Xmb;
  f32x4 acc[2][4] = {};
#pragma unroll
  for (int ks = 0; ks < 4; ++ks){
    int kb = ks * 32 + kq;
    bf16x8 a = *(const bf16x8*)(X + (size_t)(ti + r0) * 128 + kb);
#pragma unroll
    for (int pan = 0; pan < 2; ++pan)
#pragma unroll
      for (int js = 0; js < 4; ++js){
        bf16x8 b = *(const bf16x8*)(X + (size_t)(tj + pan * 64 + js * 16 + r0) * 128 + kb);
        acc[pan][js] = __builtin_amdgcn_mfma_f32_16x16x32_bf16(a, b, acc[pan][js], 0, 0, 0);
      }
  }
  // issue the full mask/label burst NOW (doesn't depend on acc); latency
  // overlaps the LDS transpose below
  const int hi = lane >> 5, c = lane & 31;
  f32x4 m[8], lb[8];
#pragma unroll
  for (int g = 0; g < 8; ++g){
    size_t idx = (size_t)(ti + g * 2 + hi) * N + tj + c * 4;
    m[g]  = __builtin_nontemporal_load((const f32x4*)(mask + idx));
    lb[g] = __builtin_nontemporal_load((const f32x4*)(labels + idx));
  }
  // transpose 16x128 wave tile through LDS; pad 132 (528B rows, 16B-aligned)
  __shared__ float tile[4][16][132];
  __shared__ float wsum[4];
  const int rb = (lane >> 4) * 4, c16 = lane & 15;
#pragma unroll
  for (int pan = 0; pan < 2; ++pan)
#pragma unroll
    for (int js = 0; js < 4; ++js)
#pragma unroll
      for (int i = 0; i < 4; ++i)
        tile[wave][rb + i][pan * 64 + js * 16 + c16] = acc[pan][js][i];
  float lsum = 0.f;
#pragma unroll
  for (int g = 0; g < 8; ++g){
    int row = g * 2 + hi;
    f32x4 a = *(const f32x4*)&tile[wave][row][c * 4];
    f32x4 pv = a * m[g];
    f32x4 d = pv - lb[g];
    lsum += d[0]*d[0] + d[1]*d[1] + d[2]*d[2] + d[3]*d[3];
    size_t idx = (size_t)(ti + row) * N + tj + c * 4;
    // pred base is at odd float offset in d_out -> scalar NT stores
    __builtin_nontemporal_store(pv[0], pred + idx);
    __builtin_nontemporal_store(pv[1], pred + idx + 1);
    __builtin_nontemporal_store(pv[2], pred + idx + 2);
    __builtin_nontemporal_store(pv[3], pred + idx + 3);
  }
  lsum = wave_sum(lsum);
  if (lane == 0) wsum[wave] = lsum;
  __syncthreads();
  if (threadIdx.x == 0)
    partial[blockIdx.y * gridDim.x + blockIdx.x] = wsum[0] + wsum[1] + wsum[2] + wsum[3];
}

__global__ __launch_bounds__(1024) void k_loss_fin(const float* __restrict__ partial,
                                                   float* __restrict__ out, float inv, int n){
  float s = 0.f;
  for (int i = threadIdx.x; i < n; i += 1024) s += partial[i];
  s = wave_sum(s);
  __shared__ float ws[16];
  if ((threadIdx.x & 63) == 0) ws[threadIdx.x >> 6] = s;
  __syncthreads();
  if (threadIdx.x == 0){
    float t = 0.f;
#pragma unroll
    for (int w = 0; w < 16; ++w) t += ws[w];
    out[0] = t * inv;
  }
}

extern "C" void kernel_launch(void* const* d_in, const int* in_sizes, int n_in,
                              void* d_out, int out_size, void* d_ws, size_t ws_size,
                              hipStream_t stream){
  const float* X      = (const float*)d_in[0];
  const int*   pe     = (const int*)d_in[1];
  const int*   ne     = (const int*)d_in[2];
  const float* labels = (const float*)d_in[3];
  const float* mask   = (const float*)d_in[4];
  const float* Wpb    = (const float*)d_in[5];
  const float* bpb    = (const float*)d_in[6];
  const float* Wnb    = (const float*)d_in[7];
  const float* bnb    = (const float*)d_in[8];
  const float* Wpd    = (const float*)d_in[9];
  const float* bpd    = (const float*)d_in[10];
  const float* Wnd    = (const float*)d_in[11];
  const float* bnd    = (const float*)d_in[12];
  const int N = in_sizes[0] / DIN;       // 8192
  const int E = in_sizes[1] / 2;         // 262144

  char* ws = (char*)d_ws;
  size_t off = 0;
  auto alloc = [&](size_t bytes){ void* p = ws + off; off = (off + bytes + 255) & ~(size_t)255; return p; };
  float* XW            = (float*)alloc((size_t)N * 256 * 4);
  float* hp            = (float*)alloc((size_t)N * 64 * 4);
  float* hn            = (float*)alloc((size_t)N * 64 * 4);
  __hip_bfloat16* Xmb  = (__hip_bfloat16*)alloc((size_t)N * 128 * 2);
  __hip_bfloat16* Xb   = (__hip_bfloat16*)alloc((size_t)N * KP * 2);
  __hip_bfloat16* Wtb  = (__hip_bfloat16*)alloc((size_t)256 * KP * 2);
  int* adjp            = (int*)alloc((size_t)E * 4);
  int* adjn            = (int*)alloc((size_t)E * 4);
  char* zbase = ws + off;                 // zeroed region start
  int* cntp            = (int*)alloc((size_t)N * 4);
  int* cntn            = (int*)alloc((size_t)N * 4);
  int* curp            = (int*)alloc((size_t)N * 4);
  int* curn            = (int*)alloc((size_t)N * 4);
  size_t zbytes = (size_t)((ws + off) - zbase);
  int* offp            = (int*)alloc((size_t)N * 4);
  int* offn            = (int*)alloc((size_t)N * 4);
  float* partial       = (float*)alloc((size_t)(N / 64) * (N / 128) * 4);
  (void)ws_size; (void)n_in; (void)out_size;

  float* out_loss = (float*)d_out;
  float* out_xmol = out_loss + 1;
  float* out_pred = out_xmol + (size_t)N * 128;

  hipMemsetAsync(zbase, 0, zbytes, stream);
  k_prep<<<N + 256 + (E + 255) / 256, 256, 0, stream>>>(X, Xb, Wpb, Wnb, Wtb,
                                                        pe, ne, cntp, cntn, E, N);
  k_gemm_base<<<dim3(4, N / 64), 256, 0, stream>>>(Xb, Wtb, XW);
  k_scan<<<2, 1024, 0, stream>>>(cntp, offp, cntn, offn, N);
  k_fill<<<(E + 255) / 256, 256, 0, stream>>>(pe, pe + E, ne, ne + E, offp, offn, curp, curn, adjp, adjn, E);
  k_base<<<N / 4, 256, 0, stream>>>(XW, adjp, offp, cntp, adjn, offn, cntn, bpb, bnb, hp, hn);
  k_deep<<<N / 4, 256, 0, stream>>>(hp, hn, adjp, offp, cntp, adjn, offn, cntn,
                                    Wpd, bpd, Wnd, bnd, out_xmol, Xmb);
  k_pred<<<dim3(N / 128, N / 64), 256, 0, stream>>>(Xmb, mask, labels, out_pred, partial, N);
  k_loss_fin<<<1, 1024, 0, stream>>>(partial, out_loss, 1.0f / ((float)N * (float)N), (N / 64) * (N / 128));
}

// Round 15
// 340.957 us; speedup vs baseline: 1.5201x; 1.0107x over previous
//
#include <hip/hip_runtime.h>
#include <hip/hip_bf16.h>

#define DIN 300
#define KP  320            // K padded to multiple of 32 for MFMA
#define NH  64

typedef __bf16 bf16x8 __attribute__((ext_vector_type(8)));
typedef float  f32x4  __attribute__((ext_vector_type(4)));
typedef short  s16x4  __attribute__((ext_vector_type(4)));

__device__ inline float wave_sum(float v){
#pragma unroll
  for (int m = 32; m >= 1; m >>= 1) v += __shfl_xor(v, m, 64);
  return v;
}

// ---------- fused prep: cvtX | cvtW | hist (independent work, one launch) ----------
__global__ __launch_bounds__(256) void k_prep(const float* __restrict__ X,
                                              __hip_bfloat16* __restrict__ Xb,
                                              const float* __restrict__ Wpb,
                                              const float* __restrict__ Wnb,
                                              __hip_bfloat16* __restrict__ Wtb,
                                              const int* __restrict__ pr, const int* __restrict__ nr,
                                              int* __restrict__ cp, int* __restrict__ cn,
                                              int E, int N){
  int b = blockIdx.x;
  if (b < N){                          // X row -> bf16 padded (vectorized: f32x4 -> 4xbf16)
    const float* xr = X + (size_t)b * DIN;           // row base 1200B = 16B aligned
    unsigned short* o = (unsigned short*)(Xb + (size_t)b * KP);
    int k = threadIdx.x;               // 80 groups of 4 elements (KP=320)
    if (k < 80){
      s16x4 v;
      if (k < 75){                     // 75*4 = 300 = DIN
        f32x4 x = *(const f32x4*)(xr + k * 4);
#pragma unroll
        for (int j = 0; j < 4; ++j){
          union { float f; unsigned u; } cv; cv.f = x[j];
          // round-to-nearest-even bf16
          unsigned r = (cv.u + 0x7FFF + ((cv.u >> 16) & 1)) >> 16;
          v[j] = (short)r;
        }
      } else v = (s16x4){0,0,0,0};
      *(s16x4*)(o + k * 4) = v;
    }
  } else if (b < N + 256){             // W col -> transposed bf16 padded
    int c = b - N;
    int sel = c >> 6, jj = c & 63;
    const float* W = (sel < 2 ? Wpb : Wnb) + (size_t)(sel & 1) * DIN * NH + jj;
    __hip_bfloat16* o = Wtb + (size_t)c * KP;
    for (int k = threadIdx.x; k < KP; k += 256)
      o[k] = __float2bfloat16(k < DIN ? W[(size_t)k * NH] : 0.f);
  } else {                             // edge histogram
    int i = (b - N - 256) * 256 + threadIdx.x;
    if (i < E){ atomicAdd(cp + pr[i], 1); atomicAdd(cn + nr[i], 1); }
  }
}

// ---------- XW[N][256] = Xb @ Wcat  (MFMA bf16, bf16 output) ----------
__global__ __launch_bounds__(256) void k_gemm_base(const __hip_bfloat16* __restrict__ Xb,
                                                   const __hip_bfloat16* __restrict__ Wtb,
                                                   __hip_bfloat16* __restrict__ XW){
  const int wave = threadIdx.x >> 6, lane = threadIdx.x & 63;
  const int ti = blockIdx.y * 64 + wave * 16;     // row tile (16 rows/wave)
  const int cj = blockIdx.x * 64;                 // col tile
  const int r0 = lane & 15, kq = (lane >> 4) * 8;
  const unsigned short* Xp = (const unsigned short*)Xb;
  const unsigned short* Wp = (const unsigned short*)Wtb;
  f32x4 acc[4] = {};
  for (int ks = 0; ks < KP / 32; ++ks){
    int kb = ks * 32 + kq;
    bf16x8 a = *(const bf16x8*)(Xp + (size_t)(ti + r0) * KP + kb);
#pragma unroll
    for (int js = 0; js < 4; ++js){
      bf16x8 b = *(const bf16x8*)(Wp + (size_t)(cj + js * 16 + r0) * KP + kb);
      acc[js] = __builtin_amdgcn_mfma_f32_16x16x32_bf16(a, b, acc[js], 0, 0, 0);
    }
  }
  const int orow = ti + (lane >> 4) * 4;
  const int oc = cj + (lane & 15);
#pragma unroll
  for (int js = 0; js < 4; ++js)
#pragma unroll
    for (int i = 0; i < 4; ++i)
      XW[(size_t)(orow + i) * 256 + oc + js * 16] = __float2bfloat16(acc[js][i]);
}

__global__ __launch_bounds__(1024) void k_scan(const int* __restrict__ c0, int* __restrict__ o0,
                                               const int* __restrict__ c1, int* __restrict__ o1, int n){
  const int* cnt = blockIdx.x ? c1 : c0;
  int* off = blockIdx.x ? o1 : o0;
  __shared__ int lds[1024];
  int t = threadIdx.x;
  int ept = n >> 10;
  int s = 0;
  for (int i = 0; i < ept; ++i) s += cnt[t * ept + i];
  lds[t] = s; __syncthreads();
  for (int d = 1; d < 1024; d <<= 1){
    int add = (t >= d) ? lds[t - d] : 0;
    __syncthreads();
    lds[t] += add;
    __syncthreads();
  }
  int base = t ? lds[t - 1] : 0;
  for (int i = 0; i < ept; ++i){ off[t * ept + i] = base; base += cnt[t * ept + i]; }
}

__global__ void k_fill(const int* __restrict__ pr, const int* __restrict__ pc,
                       const int* __restrict__ nr, const int* __restrict__ nc,
                       const int* __restrict__ op, const int* __restrict__ on,
                       int* __restrict__ curp, int* __restrict__ curn,
                       int* __restrict__ adjp, int* __restrict__ adjn, int E){
  int i = blockIdx.x * 256 + threadIdx.x;
  if (i < E){
    int r = pr[i]; int p = atomicAdd(curp + r, 1); adjp[op[r] + p] = pc[i];
    r = nr[i];     p = atomicAdd(curn + r, 1);     adjn[on[r] + p] = nc[i];
  }
}

// ---------- base layer: mean-gather + self + bias, l2norm, tanh (bf16 in/out) ----------
__device__ inline float gather_mean_bf(const __hip_bfloat16* __restrict__ XW, const int* __restrict__ adj,
                                       int base, int d, int col){
  const unsigned short* Xp = (const unsigned short*)XW;
  float s0 = 0.f, s1 = 0.f, s2 = 0.f, s3 = 0.f;
  int j = 0;
  for (; j + 8 <= d; j += 8){
    int n0 = adj[base + j],     n1 = adj[base + j + 1], n2 = adj[base + j + 2], n3 = adj[base + j + 3];
    int n4 = adj[base + j + 4], n5 = adj[base + j + 5], n6 = adj[base + j + 6], n7 = adj[base + j + 7];
    unsigned short v0 = Xp[(size_t)n0 * 256 + col], v4 = Xp[(size_t)n4 * 256 + col];
    unsigned short v1 = Xp[(size_t)n1 * 256 + col], v5 = Xp[(size_t)n5 * 256 + col];
    unsigned short v2 = Xp[(size_t)n2 * 256 + col], v6 = Xp[(size_t)n6 * 256 + col];
    unsigned short v3 = Xp[(size_t)n3 * 256 + col], v7 = Xp[(size_t)n7 * 256 + col];
    union { unsigned u; float f; } c0, c1, c2, c3, c4, c5, c6, c7;
    c0.u = (unsigned)v0 << 16; c1.u = (unsigned)v1 << 16; c2.u = (unsigned)v2 << 16; c3.u = (unsigned)v3 << 16;
    c4.u = (unsigned)v4 << 16; c5.u = (unsigned)v5 << 16; c6.u = (unsigned)v6 << 16; c7.u = (unsigned)v7 << 16;
    s0 += c0.f + c4.f; s1 += c1.f + c5.f; s2 += c2.f + c6.f; s3 += c3.f + c7.f;
  }
  for (; j < d; ++j){
    union { unsigned u; float f; } c; c.u = (unsigned)Xp[(size_t)adj[base + j] * 256 + col] << 16;
    s0 += c.f;
  }
  float s = (s0 + s1) + (s2 + s3);
  return s / (float)(d > 0 ? d : 1);
}

__global__ __launch_bounds__(256) void k_base(const __hip_bfloat16* __restrict__ XW,
    const int* __restrict__ adjp, const int* __restrict__ offp, const int* __restrict__ cntp,
    const int* __restrict__ adjn, const int* __restrict__ offn, const int* __restrict__ cntn,
    const float* __restrict__ bp, const float* __restrict__ bn,
    __hip_bfloat16* __restrict__ hp, __hip_bfloat16* __restrict__ hn){
  const int wave = threadIdx.x >> 6, lane = threadIdx.x & 63;
  const int node = blockIdx.x * 4 + wave;
  {
    float s = gather_mean_bf(XW, adjp, offp[node], cntp[node], lane);
    float pre = s + __bfloat162float(XW[(size_t)node * 256 + 64 + lane]) + bp[lane];
    float nrm = sqrtf(wave_sum(pre * pre));
    hp[(size_t)node * 64 + lane] = __float2bfloat16(tanhf(pre / fmaxf(nrm, 1e-12f)));
  }
  {
    float s = gather_mean_bf(XW, adjn, offn[node], cntn[node], lane + 128);
    float pre = s + __bfloat162float(XW[(size_t)node * 256 + 192 + lane]) + bn[lane];
    float nrm = sqrtf(wave_sum(pre * pre));
    hn[(size_t)node * 64 + lane] = __float2bfloat16(tanhf(pre / fmaxf(nrm, 1e-12f)));
  }
}

// ---------- deep layer (fused aggregates + both 192x64 GEMMs + norms + X_mol) ----------
__device__ inline float bf2f(unsigned short v){
  union { unsigned u; float f; } c; c.u = (unsigned)v << 16; return c.f;
}

__global__ __launch_bounds__(256) void k_deep(const __hip_bfloat16* __restrict__ hp, const __hip_bfloat16* __restrict__ hn,
    const int* __restrict__ adjp, const int* __restrict__ offp, const int* __restrict__ cntp,
    const int* __restrict__ adjn, const int* __restrict__ offn, const int* __restrict__ cntn,
    const float* __restrict__ Wpd, const float* __restrict__ bpd,
    const float* __restrict__ Wnd, const float* __restrict__ bnd,
    float* __restrict__ xmol, __hip_bfloat16* __restrict__ Xmb){
  const int wave = threadIdx.x >> 6, lane = threadIdx.x & 63;
  const int node = blockIdx.x * 4 + wave;
  const unsigned short* hpp = (const unsigned short*)hp;
  const unsigned short* hnp = (const unsigned short*)hn;
  const float mhp = bf2f(hpp[(size_t)node * 64 + lane]);
  const float mhn = bf2f(hnp[(size_t)node * 64 + lane]);
  float a1p = 0.f, a1n = 0.f;
  {
    int d = cntp[node], base = offp[node]; int j = 0;
    for (; j + 4 <= d; j += 4){
      int n0 = adjp[base + j], n1 = adjp[base + j + 1];
      int n2 = adjp[base + j + 2], n3 = adjp[base + j + 3];
      a1p += (bf2f(hpp[(size_t)n0 * 64 + lane]) + bf2f(hpp[(size_t)n1 * 64 + lane]))
           + (bf2f(hpp[(size_t)n2 * 64 + lane]) + bf2f(hpp[(size_t)n3 * 64 + lane]));
      a1n += (bf2f(hnp[(size_t)n0 * 64 + lane]) + bf2f(hnp[(size_t)n1 * 64 + lane]))
           + (bf2f(hnp[(size_t)n2 * 64 + lane]) + bf2f(hnp[(size_t)n3 * 64 + lane]));
    }
    for (; j < d; ++j){ int n0 = adjp[base + j]; a1p += bf2f(hpp[(size_t)n0 * 64 + lane]); a1n += bf2f(hnp[(size_t)n0 * 64 + lane]); }
    float inv = 1.f / (float)(d > 0 ? d : 1); a1p *= inv; a1n *= inv;
  }
  float a2p = 0.f, a2n = 0.f;
  {
    int d = cntn[node], base = offn[node]; int j = 0;
    for (; j + 4 <= d; j += 4){
      int n0 = adjn[base + j], n1 = adjn[base + j + 1];
      int n2 = adjn[base + j + 2], n3 = adjn[base + j + 3];
      a2p += (bf2f(hnp[(size_t)n0 * 64 + lane]) + bf2f(hnp[(size_t)n1 * 64 + lane]))
           + (bf2f(hnp[(size_t)n2 * 64 + lane]) + bf2f(hnp[(size_t)n3 * 64 + lane]));
      a2n += (bf2f(hpp[(size_t)n0 * 64 + lane]) + bf2f(hpp[(size_t)n1 * 64 + lane]))
           + (bf2f(hpp[(size_t)n2 * 64 + lane]) + bf2f(hpp[(size_t)n3 * 64 + lane]));
    }
    for (; j < d; ++j){ int n0 = adjn[base + j]; a2p += bf2f(hnp[(size_t)n0 * 64 + lane]); a2n += bf2f(hpp[(size_t)n0 * 64 + lane]); }
    float inv = 1.f / (float)(d > 0 ? d : 1); a2p *= inv; a2n *= inv;
  }
  float accp = bpd[lane], accn = bnd[lane];
#pragma unroll 4
  for (int k = 0; k < 64; ++k){
    float p1 = __shfl(a1p, k, 64), p2 = __shfl(a2p, k, 64), p3 = __shfl(mhp, k, 64);
    float q1 = __shfl(a1n, k, 64), q2 = __shfl(a2n, k, 64), q3 = __shfl(mhn, k, 64);
    accp += p1 * Wpd[k * 64 + lane] + p2 * Wpd[(64 + k) * 64 + lane] + p3 * Wpd[(128 + k) * 64 + lane];
    accn += q1 * Wnd[k * 64 + lane] + q2 * Wnd[(64 + k) * 64 + lane] + q3 * Wnd[(128 + k) * 64 + lane];
  }
  float np = sqrtf(wave_sum(accp * accp));
  float h2p = tanhf(accp / fmaxf(np, 1e-12f));
  float nn = sqrtf(wave_sum(accn * accn));
  float h2n = tanhf(accn / fmaxf(nn, 1e-12f));
  float nz = sqrtf(wave_sum(h2p * h2p + h2n * h2n));
  float xp = h2p / fmaxf(nz, 1e-12f);
  float xn = h2n / fmaxf(nz, 1e-12f);
  xmol[(size_t)node * 128 + lane] = xp;
  xmol[(size_t)node * 128 + 64 + lane] = xn;
  Xmb[(size_t)node * 128 + lane] = __float2bfloat16(xp);
  Xmb[(size_t)node * 128 + 64 + lane] = __float2bfloat16(xn);
}

// ---------- pred = (Xm @ Xm^T) * mask ; per-block loss partials ----------
// EXACT R6 structure (measured best: ~198us, 2.8 TB/s HBM + L3-served reads
// ~= 3.9 TB/s effective). FROZEN: 10 structural variants (reg-pipeline,
// LDS-DMA, occupancy-shrink, no-LDS scalar, keep-alive pins) all measured
// worse; this is the operating optimum for this mixed 2-read+1-write stream.
__global__ __launch_bounds__(256) void k_pred(const __hip_bfloat16* __restrict__ Xmb,
    const float* __restrict__ mask, const float* __restrict__ labels,
    float* __restrict__ pred, float* __restrict__ partial, int N){
  const int wave = threadIdx.x >> 6, lane = threadIdx.x & 63;
  const int ti = blockIdx.y * 64 + wave * 16;
  const int tj = blockIdx.x * 128;
  const int r0 = lane & 15, kq = (lane >> 4) * 8;
  const unsigned short* X = (const unsigned short*)Xmb;
  f32x4 acc[2][4] = {};
#pragma unroll
  for (int ks = 0; ks < 4; ++ks){
    int kb = ks * 32 + kq;
    bf16x8 a = *(const bf16x8*)(X + (size_t)(ti + r0) * 128 + kb);
#pragma unroll
    for (int pan = 0; pan < 2; ++pan)
#pragma unroll
      for (int js = 0; js < 4; ++js){
        bf16x8 b = *(const bf16x8*)(X + (size_t)(tj + pan * 64 + js * 16 + r0) * 128 + kb);
        acc[pan][js] = __builtin_amdgcn_mfma_f32_16x16x32_bf16(a, b, acc[pan][js], 0, 0, 0);
      }
  }
  // issue the full mask/label burst NOW (doesn't depend on acc); latency
  // overlaps the LDS transpose below
  const int hi = lane >> 5, c = lane & 31;
  f32x4 m[8], lb[8];
#pragma unroll
  for (int g = 0; g < 8; ++g){
    size_t idx = (size_t)(ti + g * 2 + hi) * N + tj + c * 4;
    m[g]  = __builtin_nontemporal_load((const f32x4*)(mask + idx));
    lb[g] = __builtin_nontemporal_load((const f32x4*)(labels + idx));
  }
  // transpose 16x128 wave tile through LDS; pad 132 (528B rows, 16B-aligned)
  __shared__ float tile[4][16][132];
  __shared__ float wsum[4];
  const int rb = (lane >> 4) * 4, c16 = lane & 15;
#pragma unroll
  for (int pan = 0; pan < 2; ++pan)
#pragma unroll
    for (int js = 0; js < 4; ++js)
#pragma unroll
      for (int i = 0; i < 4; ++i)
        tile[wave][rb + i][pan * 64 + js * 16 + c16] = acc[pan][js][i];
  float lsum = 0.f;
#pragma unroll
  for (int g = 0; g < 8; ++g){
    int row = g * 2 + hi;
    f32x4 a = *(const f32x4*)&tile[wave][row][c * 4];
    f32x4 pv = a * m[g];
    f32x4 d = pv - lb[g];
    lsum += d[0]*d[0] + d[1]*d[1] + d[2]*d[2] + d[3]*d[3];
    size_t idx = (size_t)(ti + row) * N + tj + c * 4;
    // pred base is at odd float offset in d_out -> scalar NT stores
    __builtin_nontemporal_store(pv[0], pred + idx);
    __builtin_nontemporal_store(pv[1], pred + idx + 1);
    __builtin_nontemporal_store(pv[2], pred + idx + 2);
    __builtin_nontemporal_store(pv[3], pred + idx + 3);
  }
  lsum = wave_sum(lsum);
  if (lane == 0) wsum[wave] = lsum;
  __syncthreads();
  if (threadIdx.x == 0)
    partial[blockIdx.y * gridDim.x + blockIdx.x] = wsum[0] + wsum[1] + wsum[2] + wsum[3];
}

__global__ __launch_bounds__(1024) void k_loss_fin(const float* __restrict__ partial,
                                                   float* __restrict__ out, float inv, int n){
  float s = 0.f;
  for (int i = threadIdx.x; i < n; i += 1024) s += partial[i];
  s = wave_sum(s);
  __shared__ float ws[16];
  if ((threadIdx.x & 63) == 0) ws[threadIdx.x >> 6] = s;
  __syncthreads();
  if (threadIdx.x == 0){
    float t = 0.f;
#pragma unroll
    for (int w = 0; w < 16; ++w) t += ws[w];
    out[0] = t * inv;
  }
}

extern "C" void kernel_launch(void* const* d_in, const int* in_sizes, int n_in,
                              void* d_out, int out_size, void* d_ws, size_t ws_size,
                              hipStream_t stream){
  const float* X      = (const float*)d_in[0];
  const int*   pe     = (const int*)d_in[1];
  const int*   ne     = (const int*)d_in[2];
  const float* labels = (const float*)d_in[3];
  const float* mask   = (const float*)d_in[4];
  const float* Wpb    = (const float*)d_in[5];
  const float* bpb    = (const float*)d_in[6];
  const float* Wnb    = (const float*)d_in[7];
  const float* bnb    = (const float*)d_in[8];
  const float* Wpd    = (const float*)d_in[9];
  const float* bpd    = (const float*)d_in[10];
  const float* Wnd    = (const float*)d_in[11];
  const float* bnd    = (const float*)d_in[12];
  const int N = in_sizes[0] / DIN;       // 8192
  const int E = in_sizes[1] / 2;         // 262144

  char* ws = (char*)d_ws;
  size_t off = 0;
  auto alloc = [&](size_t bytes){ void* p = ws + off; off = (off + bytes + 255) & ~(size_t)255; return p; };
  __hip_bfloat16* XW   = (__hip_bfloat16*)alloc((size_t)N * 256 * 2);
  __hip_bfloat16* hp   = (__hip_bfloat16*)alloc((size_t)N * 64 * 2);
  __hip_bfloat16* hn   = (__hip_bfloat16*)alloc((size_t)N * 64 * 2);
  __hip_bfloat16* Xmb  = (__hip_bfloat16*)alloc((size_t)N * 128 * 2);
  __hip_bfloat16* Xb   = (__hip_bfloat16*)alloc((size_t)N * KP * 2);
  __hip_bfloat16* Wtb  = (__hip_bfloat16*)alloc((size_t)256 * KP * 2);
  int* adjp            = (int*)alloc((size_t)E * 4);
  int* adjn            = (int*)alloc((size_t)E * 4);
  char* zbase = ws + off;                 // zeroed region start
  int* cntp            = (int*)alloc((size_t)N * 4);
  int* cntn            = (int*)alloc((size_t)N * 4);
  int* curp            = (int*)alloc((size_t)N * 4);
  int* curn            = (int*)alloc((size_t)N * 4);
  size_t zbytes = (size_t)((ws + off) - zbase);
  int* offp            = (int*)alloc((size_t)N * 4);
  int* offn            = (int*)alloc((size_t)N * 4);
  float* partial       = (float*)alloc((size_t)(N / 64) * (N / 128) * 4);
  (void)ws_size; (void)n_in; (void)out_size;

  float* out_loss = (float*)d_out;
  float* out_xmol = out_loss + 1;
  float* out_pred = out_xmol + (size_t)N * 128;

  hipMemsetAsync(zbase, 0, zbytes, stream);
  k_prep<<<N + 256 + (E + 255) / 256, 256, 0, stream>>>(X, Xb, Wpb, Wnb, Wtb,
                                                        pe, ne, cntp, cntn, E, N);
  k_gemm_base<<<dim3(4, N / 64), 256, 0, stream>>>(Xb, Wtb, XW);
  k_scan<<<2, 1024, 0, stream>>>(cntp, offp, cntn, offn, N);
  k_fill<<<(E + 255) / 256, 256, 0, stream>>>(pe, pe + E, ne, ne + E, offp, offn, curp, curn, adjp, adjn, E);
  k_base<<<N / 4, 256, 0, stream>>>(XW, adjp, offp, cntp, adjn, offn, cntn, bpb, bnb, hp, hn);
  k_deep<<<N / 4, 256, 0, stream>>>(hp, hn, adjp, offp, cntp, adjn, offn, cntn,
                                    Wpd, bpd, Wnd, bnd, out_xmol, Xmb);
  k_pred<<<dim3(N / 128, N / 64), 256, 0, stream>>>(Xmb, mask, labels, out_pred, partial, N);
  k_loss_fin<<<1, 1024, 0, stream>>>(partial, out_loss, 1.0f / ((float)N * (float)N), (N / 64) * (N / 128));
}